// Round 1
// baseline (383.890 us; speedup 1.0000x reference)
//
#include <hip/hip_runtime.h>
#include <math.h>

#define HH 96
#define WW 96
#define CC 64
#define NH 4
#define HD 16
#define KS 13
#define KK (KS*KS)
#define NTOK (HH*WW)

// ---------------- LayerNorm: one wave (64 lanes) per token ----------------
__global__ __launch_bounds__(256) void ln_kernel(const float* __restrict__ x,
                                                 const float* __restrict__ g,
                                                 const float* __restrict__ b,
                                                 float* __restrict__ out) {
    int wave = threadIdx.x >> 6;
    int lane = threadIdx.x & 63;
    int token = blockIdx.x * 4 + wave;
    float v = x[token * CC + lane];
    float s = v;
    #pragma unroll
    for (int o = 1; o < 64; o <<= 1) s += __shfl_xor(s, o);
    float mu = s * (1.0f / 64.0f);
    float d = v - mu;
    float s2 = d * d;
    #pragma unroll
    for (int o = 1; o < 64; o <<= 1) s2 += __shfl_xor(s2, o);
    float var = s2 * (1.0f / 64.0f);
    out[token * CC + lane] = d * rsqrtf(var + 1e-5f) * g[lane] + b[lane];
}

// ---------------- Generic GEMM: out[M,NC] = A[M,K] @ W[K,NC] + bias ----------------
template<int K, int NC, bool GELU_ACT, bool RESID, bool QSCALE>
__global__ __launch_bounds__(256) void gemm_kernel(const float* __restrict__ A,
                                                   const float* __restrict__ W,
                                                   const float* __restrict__ bias,
                                                   const float* __restrict__ resid,
                                                   float* __restrict__ out) {
    const int TM = 32;
    __shared__ float As[TM][K];
    int t0 = blockIdx.x * TM;
    for (int i = threadIdx.x; i < TM * K; i += 256) {
        int r = i / K, c = i % K;
        As[r][c] = A[(t0 + r) * K + c];
    }
    __syncthreads();
    for (int i = threadIdx.x; i < TM * NC; i += 256) {
        int r = i / NC, c = i % NC;
        float acc = bias[c];
        const float* wcol = W + c;
        #pragma unroll 8
        for (int k = 0; k < K; k++) acc += As[r][k] * wcol[k * NC];
        if (QSCALE) { if (c < CC) acc *= 0.25f; }  // q * hd^-0.5
        if (GELU_ACT) acc = 0.5f * acc * (1.0f + erff(acc * 0.70710678118f));
        if (RESID) acc += resid[(t0 + r) * NC + c];
        out[(t0 + r) * NC + c] = acc;
    }
}

// ---------------- Neighborhood attention: one wave per token ----------------
// qkv layout per token: [q(0..63) | k(64..127) | v(128..191)], head-major (n*16+d)
__global__ __launch_bounds__(256) void na_attn_kernel(const float* __restrict__ qkv,
                                                      const float* __restrict__ rpb,
                                                      float* __restrict__ out) {
    int wave = threadIdx.x >> 6;
    int lane = threadIdx.x & 63;
    int token = blockIdx.x * 4 + wave;
    int head = lane >> 4;
    int dim  = lane & 15;

    int y = token / WW, x = token % WW;
    int gh = y % 3, ih = y / 3;
    int gw = x % 3, iw = x / 3;
    int sh = ih - 6; sh = sh < 0 ? 0 : (sh > 19 ? 19 : sh);
    int sw = iw - 6; sw = sw < 0 ? 0 : (sw > 19 ? 19 : sw);

    float q = qkv[token * 192 + head * HD + dim];

    __shared__ float lg[4][NH][KK];

    // pass 1: logits = q.k (reduced over 16 lanes) + bias
    for (int kh = 0; kh < KS; kh++) {
        int ny = gh + 3 * (sh + kh);
        int rh = sh + kh - ih + 12;
        for (int kw = 0; kw < KS; kw++) {
            int nx = gw + 3 * (sw + kw);
            int nt = ny * WW + nx;
            float kv = qkv[nt * 192 + CC + head * HD + dim];
            float p = q * kv;
            p += __shfl_xor(p, 1);
            p += __shfl_xor(p, 2);
            p += __shfl_xor(p, 4);
            p += __shfl_xor(p, 8);
            if (dim == 0) {
                int rw = sw + kw - iw + 12;
                lg[wave][head][kh * KS + kw] = p + rpb[(head * 25 + rh) * 25 + rw];
            }
        }
    }
    __syncthreads();

    // softmax over 169 entries per head: 16 lanes cooperate
    float m = -1e30f;
    for (int kk = dim; kk < KK; kk += 16) m = fmaxf(m, lg[wave][head][kk]);
    #pragma unroll
    for (int o = 1; o < 16; o <<= 1) m = fmaxf(m, __shfl_xor(m, o));
    float s = 0.0f;
    for (int kk = dim; kk < KK; kk += 16) {
        float e = __expf(lg[wave][head][kk] - m);
        lg[wave][head][kk] = e;
        s += e;
    }
    #pragma unroll
    for (int o = 1; o < 16; o <<= 1) s += __shfl_xor(s, o);
    float inv = 1.0f / s;
    __syncthreads();

    // pass 2: out = attn . v
    float acc = 0.0f;
    for (int kh = 0; kh < KS; kh++) {
        int ny = gh + 3 * (sh + kh);
        for (int kw = 0; kw < KS; kw++) {
            int nx = gw + 3 * (sw + kw);
            int nt = ny * WW + nx;
            float vv = qkv[nt * 192 + 2 * CC + head * HD + dim];
            acc += lg[wave][head][kh * KS + kw] * vv;
        }
    }
    out[token * CC + head * HD + dim] = acc * inv;
}

extern "C" void kernel_launch(void* const* d_in, const int* in_sizes, int n_in,
                              void* d_out, int out_size, void* d_ws, size_t ws_size,
                              hipStream_t stream) {
    const float* x       = (const float*)d_in[0];
    const float* norm1_g = (const float*)d_in[1];
    const float* norm1_b = (const float*)d_in[2];
    const float* qkv_w   = (const float*)d_in[3];
    const float* qkv_b   = (const float*)d_in[4];
    const float* rpb     = (const float*)d_in[5];
    const float* proj_w  = (const float*)d_in[6];
    const float* proj_b  = (const float*)d_in[7];
    const float* norm2_g = (const float*)d_in[8];
    const float* norm2_b = (const float*)d_in[9];
    const float* fc1_w   = (const float*)d_in[10];
    const float* fc1_b   = (const float*)d_in[11];
    const float* fc2_w   = (const float*)d_in[12];
    const float* fc2_b   = (const float*)d_in[13];
    float* out = (float*)d_out;

    float* ws = (float*)d_ws;
    float* h1       = ws;                      // 9216*64
    float* qkv      = h1 + NTOK * CC;          // 9216*192
    float* attn_out = qkv + NTOK * 192;        // 9216*64
    float* x2       = attn_out + NTOK * CC;    // 9216*64
    float* h2       = x2 + NTOK * CC;          // 9216*64
    float* hidden   = h2 + NTOK * CC;          // 9216*256

    dim3 blk(256);
    // 1. LN1
    ln_kernel<<<NTOK / 4, blk, 0, stream>>>(x, norm1_g, norm1_b, h1);
    // 2. qkv = h1 @ qkv_w + qkv_b   (q pre-scaled)
    gemm_kernel<64, 192, false, false, true><<<NTOK / 32, blk, 0, stream>>>(h1, qkv_w, qkv_b, nullptr, qkv);
    // 3. neighborhood attention
    na_attn_kernel<<<NTOK / 4, blk, 0, stream>>>(qkv, rpb, attn_out);
    // 4. x2 = x + attn_out @ proj_w + proj_b
    gemm_kernel<64, 64, false, true, false><<<NTOK / 32, blk, 0, stream>>>(attn_out, proj_w, proj_b, x, x2);
    // 5. LN2
    ln_kernel<<<NTOK / 4, blk, 0, stream>>>(x2, norm2_g, norm2_b, h2);
    // 6. hidden = gelu(h2 @ fc1_w + fc1_b)
    gemm_kernel<64, 256, true, false, false><<<NTOK / 32, blk, 0, stream>>>(h2, fc1_w, fc1_b, nullptr, hidden);
    // 7. out = x2 + hidden @ fc2_w + fc2_b
    gemm_kernel<256, 64, false, true, false><<<NTOK / 32, blk, 0, stream>>>(hidden, fc2_w, fc2_b, x2, out);
}

// Round 2
// 213.827 us; speedup vs baseline: 1.7953x; 1.7953x over previous
//
#include <hip/hip_runtime.h>
#include <math.h>

#define HH 96
#define WW 96
#define CC 64
#define NH 4
#define HD 16
#define KS 13
#define KK (KS*KS)
#define NTOK (HH*WW)

// ---------------- LayerNorm: one wave (64 lanes) per token ----------------
__global__ __launch_bounds__(256) void ln_kernel(const float* __restrict__ x,
                                                 const float* __restrict__ g,
                                                 const float* __restrict__ b,
                                                 float* __restrict__ out) {
    int wave = threadIdx.x >> 6;
    int lane = threadIdx.x & 63;
    int token = blockIdx.x * 4 + wave;
    float v = x[token * CC + lane];
    float s = v;
    #pragma unroll
    for (int o = 1; o < 64; o <<= 1) s += __shfl_xor(s, o);
    float mu = s * (1.0f / 64.0f);
    float d = v - mu;
    float s2 = d * d;
    #pragma unroll
    for (int o = 1; o < 64; o <<= 1) s2 += __shfl_xor(s2, o);
    float var = s2 * (1.0f / 64.0f);
    out[token * CC + lane] = d * rsqrtf(var + 1e-5f) * g[lane] + b[lane];
}

// ---------------- Register-tiled GEMM: out[M,NC] = A[M,K] @ W[K,NC] + bias ----
// Block computes a 32 (rows) x 64 (cols) tile. 256 threads = 16 col-groups x
// 16 row-groups; each thread: 2 rows x 4 cols (float4). A staged transposed in
// LDS with +2 pad -> conflict-free float2 reads, aligned (34 even, r0 even).
template<int K, int NC, bool GELU_ACT, bool RESID, bool QSCALE>
__global__ __launch_bounds__(256) void gemm_kernel(const float* __restrict__ A,
                                                   const float* __restrict__ W,
                                                   const float* __restrict__ bias,
                                                   const float* __restrict__ resid,
                                                   float* __restrict__ out) {
    __shared__ float Ast[K][34];
    const int t0 = blockIdx.x * 32;
    const int tc = threadIdx.x & 15;
    const int tr = threadIdx.x >> 4;
    const int r0 = tr * 2;
    const int c  = blockIdx.y * 64 + tc * 4;

    // stage A tile transposed (coalesced global read, 2-way-bank LDS write = free)
    for (int i = threadIdx.x; i < 32 * K; i += 256) {
        int r = i / K, cc = i % K;
        Ast[cc][r] = A[t0 * K + i];
    }
    __syncthreads();

    float4 b4 = *(const float4*)&bias[c];
    float4 acc0 = b4, acc1 = b4;
    #pragma unroll 8
    for (int k = 0; k < K; k++) {
        float2 a = *(const float2*)&Ast[k][r0];
        float4 w = *(const float4*)&W[k * NC + c];
        acc0.x += a.x * w.x; acc0.y += a.x * w.y; acc0.z += a.x * w.z; acc0.w += a.x * w.w;
        acc1.x += a.y * w.x; acc1.y += a.y * w.y; acc1.z += a.y * w.z; acc1.w += a.y * w.w;
    }

    if (QSCALE && blockIdx.y == 0) {  // q section (cols 0..63) scaled by hd^-0.5
        acc0.x *= 0.25f; acc0.y *= 0.25f; acc0.z *= 0.25f; acc0.w *= 0.25f;
        acc1.x *= 0.25f; acc1.y *= 0.25f; acc1.z *= 0.25f; acc1.w *= 0.25f;
    }
    if (GELU_ACT) {
        #define GELU1(v) v = 0.5f * v * (1.0f + erff(v * 0.70710678118f))
        GELU1(acc0.x); GELU1(acc0.y); GELU1(acc0.z); GELU1(acc0.w);
        GELU1(acc1.x); GELU1(acc1.y); GELU1(acc1.z); GELU1(acc1.w);
        #undef GELU1
    }
    if (RESID) {
        float4 r0v = *(const float4*)&resid[(t0 + r0) * NC + c];
        float4 r1v = *(const float4*)&resid[(t0 + r0 + 1) * NC + c];
        acc0.x += r0v.x; acc0.y += r0v.y; acc0.z += r0v.z; acc0.w += r0v.w;
        acc1.x += r1v.x; acc1.y += r1v.y; acc1.z += r1v.z; acc1.w += r1v.w;
    }
    *(float4*)&out[(t0 + r0) * NC + c] = acc0;
    *(float4*)&out[(t0 + r0 + 1) * NC + c] = acc1;
}

// ---------------- Neighborhood attention: one wave per token, single pass ----
// qkv per token: [q(0..63) | k(64..127) | v(128..191)], head-major (n*16+d).
// Logits are small (|p+bias| < ~2), so softmax without max-shift is exact.
__global__ __launch_bounds__(256) void na_attn_kernel(const float* __restrict__ qkv,
                                                      const float* __restrict__ rpb,
                                                      float* __restrict__ out) {
    int wave = threadIdx.x >> 6;
    int lane = threadIdx.x & 63;
    int token = blockIdx.x * 4 + wave;
    int head = lane >> 4;
    int dim  = lane & 15;

    int y = token / WW, x = token - y * WW;
    int gh = y % 3, ih = y / 3;
    int gw = x % 3, iw = x / 3;
    int sh = ih - 6; sh = sh < 0 ? 0 : (sh > 19 ? 19 : sh);
    int sw = iw - 6; sw = sw < 0 ? 0 : (sw > 19 ? 19 : sw);

    int co = head * HD + dim;
    float q = qkv[token * 192 + co];
    const float* bias_h = rpb + head * 625 + (sw - iw + 12);

    float acc = 0.0f, s = 0.0f;
    for (int kh = 0; kh < KS; kh++) {
        int ny = gh + 3 * (sh + kh);
        int rh = sh + kh - ih + 12;
        const float* kp = qkv + (ny * WW + gw + 3 * sw) * 192 + 64 + co;
        const float* bp = bias_h + rh * 25;
        #pragma unroll
        for (int kw = 0; kw < KS; kw++) {
            float kv = kp[kw * 576];        // k of neighbor
            float vv = kp[kw * 576 + 64];   // v of neighbor
            float p = q * kv;
            p += __shfl_xor(p, 1);
            p += __shfl_xor(p, 2);
            p += __shfl_xor(p, 4);
            p += __shfl_xor(p, 8);
            float e = __expf(p + bp[kw]);
            s += e;
            acc += e * vv;
        }
    }
    out[token * CC + co] = acc / s;
}

extern "C" void kernel_launch(void* const* d_in, const int* in_sizes, int n_in,
                              void* d_out, int out_size, void* d_ws, size_t ws_size,
                              hipStream_t stream) {
    const float* x       = (const float*)d_in[0];
    const float* norm1_g = (const float*)d_in[1];
    const float* norm1_b = (const float*)d_in[2];
    const float* qkv_w   = (const float*)d_in[3];
    const float* qkv_b   = (const float*)d_in[4];
    const float* rpb     = (const float*)d_in[5];
    const float* proj_w  = (const float*)d_in[6];
    const float* proj_b  = (const float*)d_in[7];
    const float* norm2_g = (const float*)d_in[8];
    const float* norm2_b = (const float*)d_in[9];
    const float* fc1_w   = (const float*)d_in[10];
    const float* fc1_b   = (const float*)d_in[11];
    const float* fc2_w   = (const float*)d_in[12];
    const float* fc2_b   = (const float*)d_in[13];
    float* out = (float*)d_out;

    float* ws = (float*)d_ws;
    float* h1       = ws;                      // 9216*64
    float* qkv      = h1 + NTOK * CC;          // 9216*192
    float* attn_out = qkv + NTOK * 192;        // 9216*64
    float* x2       = attn_out + NTOK * CC;    // 9216*64
    float* h2       = x2 + NTOK * CC;          // 9216*64
    float* hidden   = h2 + NTOK * CC;          // 9216*256

    dim3 blk(256);
    // 1. LN1
    ln_kernel<<<NTOK / 4, blk, 0, stream>>>(x, norm1_g, norm1_b, h1);
    // 2. qkv = h1 @ qkv_w + qkv_b   (q pre-scaled)
    gemm_kernel<64, 192, false, false, true><<<dim3(NTOK / 32, 3), blk, 0, stream>>>(h1, qkv_w, qkv_b, nullptr, qkv);
    // 3. neighborhood attention (single pass, no LDS)
    na_attn_kernel<<<NTOK / 4, blk, 0, stream>>>(qkv, rpb, attn_out);
    // 4. x2 = x + attn_out @ proj_w + proj_b
    gemm_kernel<64, 64, false, true, false><<<dim3(NTOK / 32, 1), blk, 0, stream>>>(attn_out, proj_w, proj_b, x, x2);
    // 5. LN2
    ln_kernel<<<NTOK / 4, blk, 0, stream>>>(x2, norm2_g, norm2_b, h2);
    // 6. hidden = gelu(h2 @ fc1_w + fc1_b)
    gemm_kernel<64, 256, true, false, false><<<dim3(NTOK / 32, 4), blk, 0, stream>>>(h2, fc1_w, fc1_b, nullptr, hidden);
    // 7. out = x2 + hidden @ fc2_w + fc2_b
    gemm_kernel<256, 64, false, true, false><<<dim3(NTOK / 32, 1), blk, 0, stream>>>(hidden, fc2_w, fc2_b, x2, out);
}